// Round 2
// baseline (35335.477 us; speedup 1.0000x reference)
//
#include <hip/hip_runtime.h>
#include <math.h>

#define B_    32
#define S_    512
#define EMB_  512
#define HID_  1024
#define LAB_  64
#define M_    (B_ * S_)

// ---------------------------------------------------------------------------
// Generic fp32 tiled GEMM with optional row-gather (embedding lookup) on A:
//   C[m][n] = dot(Arow(m), W[n][:]) + bias[n] (+ bias2[n])
//   W row-major [N,K]  -> computes A @ W^T
// Tiles: BM=BN=64, BK=16, 256 threads, 4x4 outputs/thread.
// ---------------------------------------------------------------------------
__global__ __launch_bounds__(256) void gemm_bias(
    const float* __restrict__ A, const int* __restrict__ tokens,
    const float* __restrict__ W, const float* __restrict__ bias,
    const float* __restrict__ bias2, float* __restrict__ C,
    int M, int K, int N)
{
    __shared__ float As[64][17];
    __shared__ float Ws[64][17];

    const int tid = threadIdx.x;
    const int tx  = tid & 15;
    const int ty  = tid >> 4;
    const int n0  = blockIdx.x * 64;
    const int m0  = blockIdx.y * 64;

    const int lrow = tid >> 2;
    const int lk   = (tid & 3) << 2;

    const int arow_idx = tokens ? tokens[m0 + lrow] : (m0 + lrow);
    const float* __restrict__ arow = A + (size_t)arow_idx * K;
    const float* __restrict__ wrow = W + (size_t)(n0 + lrow) * K;

    float bs[4];
#pragma unroll
    for (int j = 0; j < 4; ++j) {
        int n = n0 + tx * 4 + j;
        bs[j] = bias[n] + (bias2 ? bias2[n] : 0.0f);
    }

    float acc[4][4] = {};

    for (int k0 = 0; k0 < K; k0 += 16) {
        const float4 av = *(const float4*)(arow + k0 + lk);
        const float4 wv = *(const float4*)(wrow + k0 + lk);
        __syncthreads();   // prev iteration's readers done
        As[lrow][lk + 0] = av.x; As[lrow][lk + 1] = av.y;
        As[lrow][lk + 2] = av.z; As[lrow][lk + 3] = av.w;
        Ws[lrow][lk + 0] = wv.x; Ws[lrow][lk + 1] = wv.y;
        Ws[lrow][lk + 2] = wv.z; Ws[lrow][lk + 3] = wv.w;
        __syncthreads();

#pragma unroll
        for (int kk = 0; kk < 16; ++kk) {
            float a[4], b[4];
#pragma unroll
            for (int i = 0; i < 4; ++i) a[i] = As[ty * 4 + i][kk];
#pragma unroll
            for (int j = 0; j < 4; ++j) b[j] = Ws[tx * 4 + j][kk];
#pragma unroll
            for (int i = 0; i < 4; ++i)
#pragma unroll
                for (int j = 0; j < 4; ++j)
                    acc[i][j] += a[i] * b[j];
        }
    }

#pragma unroll
    for (int i = 0; i < 4; ++i) {
        const int m = m0 + ty * 4 + i;
        float4 v;
        v.x = acc[i][0] + bs[0];
        v.y = acc[i][1] + bs[1];
        v.z = acc[i][2] + bs[2];
        v.w = acc[i][3] + bs[3];
        *(float4*)(C + (size_t)m * N + n0 + tx * 4) = v;
    }
}

// ---------------------------------------------------------------------------
// Repack W_hh [H][H] row-major -> WT [H/4][H] of float4:
//   WT[kb][j] = { W[j][4kb], W[j][4kb+1], W[j][4kb+2], W[j][4kb+3] }
// so the scan's per-k loads are coalesced across the j (thread) dimension.
// Grid: HID_ blocks (one per row j) x 256 threads (one per kb).
// ---------------------------------------------------------------------------
__global__ __launch_bounds__(256) void repack_whh(
    const float* __restrict__ W, float4* __restrict__ WT)
{
    const int j = blockIdx.x;      // 0..1023
    const int t = threadIdx.x;     // 0..255  (kb)
    const float4 v = *(const float4*)(W + (size_t)j * HID_ + 4 * t);
    WT[(size_t)t * HID_ + j] = v;
}

// ---------------------------------------------------------------------------
// Sequential RNN scan, one workgroup per batch (sync-free across WGs).
// Thread j owns neuron j. IN-PLACE: x holds xp on entry, h on exit.
// Coalesced weight reads via WT layout; h_{t-1} broadcast from LDS.
// ---------------------------------------------------------------------------
__global__ __launch_bounds__(1024) void rnn_scan2(
    const float4* __restrict__ WT,   // [HID_/4][HID_] packed
    float* __restrict__ x)           // [B,S,H]  xp -> h in place
{
    __shared__ float h[HID_];
    const int b = blockIdx.x;
    const int j = threadIdx.x;

    h[j] = 0.0f;
    __syncthreads();

    float* __restrict__ xb = x + (size_t)b * S_ * HID_;
    const float4* __restrict__ wp = WT + j;

    for (int t = 0; t < S_; ++t) {
        float acc  = xb[(size_t)t * HID_ + j];
        float acc2 = 0.0f;
#pragma unroll 8
        for (int kb = 0; kb < HID_ / 4; kb += 2) {
            const float4 w0 = wp[(size_t)kb * HID_];
            const float4 h0 = *(const float4*)(&h[4 * kb]);
            const float4 w1 = wp[(size_t)(kb + 1) * HID_];
            const float4 h1 = *(const float4*)(&h[4 * kb + 4]);
            acc  += w0.x * h0.x + w0.y * h0.y + w0.z * h0.z + w0.w * h0.w;
            acc2 += w1.x * h1.x + w1.y * h1.y + w1.z * h1.z + w1.w * h1.w;
        }
        const float hn = tanhf(acc + acc2);
        __syncthreads();             // all reads of h_{t-1} complete
        h[j] = hn;
        xb[(size_t)t * HID_ + j] = hn;
        __syncthreads();             // h_t visible before next step
    }
}

// simple float4 d2d copy (chunk bounce-back)
__global__ __launch_bounds__(256) void copy4(
    const float4* __restrict__ src, float4* __restrict__ dst, int n4)
{
    const int i = blockIdx.x * 256 + threadIdx.x;
    if (i < n4) dst[i] = src[i];
}

extern "C" void kernel_launch(void* const* d_in, const int* in_sizes, int n_in,
                              void* d_out, int out_size, void* d_ws, size_t ws_size,
                              hipStream_t stream)
{
    const int*   tokens = (const int*)  d_in[0];
    const float* emb    = (const float*)d_in[1];
    const float* W_ih0  = (const float*)d_in[2];
    const float* W_hh0  = (const float*)d_in[3];
    const float* b_ih0  = (const float*)d_in[4];
    const float* b_hh0  = (const float*)d_in[5];
    const float* W_ih1  = (const float*)d_in[6];
    const float* W_hh1  = (const float*)d_in[7];
    const float* b_ih1  = (const float*)d_in[8];
    const float* b_hh1  = (const float*)d_in[9];
    const float* W_out  = (const float*)d_in[10];
    const float* b_out  = (const float*)d_in[11];
    float* out = (float*)d_out;

    // EXACTLY ONE [B,S,H] fp32 buffer (64 MiB) — round-1 used 128 MiB and
    // (theory) overran ws_size, permanently corrupting adjacent allocations.
    float* buf = (float*)d_ws;

    // d_out (4 MiB == 1024x1024 floats) doubles as scratch: WT repack target
    // and xp1 chunk bounce buffer. It is fully rewritten by the final GEMM.
    float4* WT  = (float4*)d_out;
    float*  tmp = (float*)d_out;

    // 1) xp0 = gather(emb,tokens) @ W_ih0^T + b_ih0 + b_hh0   -> buf
    gemm_bias<<<dim3(HID_ / 64, M_ / 64), 256, 0, stream>>>(
        emb, tokens, W_ih0, b_ih0, b_hh0, buf, M_, EMB_, HID_);

    // 2) scan layer 0 (in place on buf)
    repack_whh<<<HID_, 256, 0, stream>>>(W_hh0, WT);
    rnn_scan2<<<B_, 1024, 0, stream>>>(WT, buf);

    // 3) xp1 = h0 @ W_ih1^T + b_ih1 + b_hh1, chunked in-place via d_out.
    //    Row m of xp1 depends only on row m of h0, so chunk gemm -> copyback
    //    over the same rows is hazard-free (kernels are stream-ordered).
    for (int c = 0; c < 16; ++c) {
        const float* Ac = buf + (size_t)c * 1024 * HID_;
        gemm_bias<<<dim3(HID_ / 64, 1024 / 64), 256, 0, stream>>>(
            Ac, nullptr, W_ih1, b_ih1, b_hh1, tmp, 1024, HID_, HID_);
        copy4<<<1024, 256, 0, stream>>>(
            (const float4*)tmp, (float4*)(buf + (size_t)c * 1024 * HID_),
            1024 * HID_ / 4);
    }

    // 4) scan layer 1 (in place on buf)
    repack_whh<<<HID_, 256, 0, stream>>>(W_hh1, WT);
    rnn_scan2<<<B_, 1024, 0, stream>>>(WT, buf);

    // 5) out = h1 @ W_out^T + b_out  (fully rewrites d_out)
    gemm_bias<<<dim3(LAB_ / 64, M_ / 64), 256, 0, stream>>>(
        buf, nullptr, W_out, b_out, nullptr, out, M_, HID_, LAB_);
}

// Round 3
// 9038.833 us; speedup vs baseline: 3.9093x; 3.9093x over previous
//
#include <hip/hip_runtime.h>
#include <math.h>

#define B_    32
#define S_    512
#define EMB_  512
#define HID_  1024
#define LAB_  64
#define M_    (B_ * S_)

// ---------------------------------------------------------------------------
// Barrier state: device globals (zero-initialized at module load). Each scan
// launch leaves them at 0 again (ack-based reset), so graph replays and fresh
// launches always start clean. 256-B padding per counter to avoid line ping.
// ---------------------------------------------------------------------------
struct PadCnt { unsigned v; unsigned pad[63]; };
__device__ PadCnt g_cnt[8];
__device__ PadCnt g_ack[8];

__device__ __forceinline__ float aload(const float* p) {
    return __hip_atomic_load((float*)p, __ATOMIC_RELAXED, __HIP_MEMORY_SCOPE_AGENT);
}
__device__ __forceinline__ void astore(float* p, float v) {
    __hip_atomic_store(p, v, __ATOMIC_RELAXED, __HIP_MEMORY_SCOPE_AGENT);
}

// ---------------------------------------------------------------------------
// fp32 tiled GEMM with optional row-gather on A (from round 2, unchanged):
//   C[m][n] = dot(Arow(m), W[n][:]) + bias[n] (+ bias2[n]),  W row-major [N,K]
// ---------------------------------------------------------------------------
__global__ __launch_bounds__(256) void gemm_bias(
    const float* __restrict__ A, const int* __restrict__ tokens,
    const float* __restrict__ W, const float* __restrict__ bias,
    const float* __restrict__ bias2, float* __restrict__ C,
    int M, int K, int N)
{
    __shared__ float As[64][17];
    __shared__ float Ws[64][17];

    const int tid = threadIdx.x;
    const int tx  = tid & 15;
    const int ty  = tid >> 4;
    const int n0  = blockIdx.x * 64;
    const int m0  = blockIdx.y * 64;

    const int lrow = tid >> 2;
    const int lk   = (tid & 3) << 2;

    const int arow_idx = tokens ? tokens[m0 + lrow] : (m0 + lrow);
    const float* __restrict__ arow = A + (size_t)arow_idx * K;
    const float* __restrict__ wrow = W + (size_t)(n0 + lrow) * K;

    float bs[4];
#pragma unroll
    for (int j = 0; j < 4; ++j) {
        int n = n0 + tx * 4 + j;
        bs[j] = bias[n] + (bias2 ? bias2[n] : 0.0f);
    }

    float acc[4][4] = {};

    for (int k0 = 0; k0 < K; k0 += 16) {
        const float4 av = *(const float4*)(arow + k0 + lk);
        const float4 wv = *(const float4*)(wrow + k0 + lk);
        __syncthreads();
        As[lrow][lk + 0] = av.x; As[lrow][lk + 1] = av.y;
        As[lrow][lk + 2] = av.z; As[lrow][lk + 3] = av.w;
        Ws[lrow][lk + 0] = wv.x; Ws[lrow][lk + 1] = wv.y;
        Ws[lrow][lk + 2] = wv.z; Ws[lrow][lk + 3] = wv.w;
        __syncthreads();

#pragma unroll
        for (int kk = 0; kk < 16; ++kk) {
            float a[4], b[4];
#pragma unroll
            for (int i = 0; i < 4; ++i) a[i] = As[ty * 4 + i][kk];
#pragma unroll
            for (int j = 0; j < 4; ++j) b[j] = Ws[tx * 4 + j][kk];
#pragma unroll
            for (int i = 0; i < 4; ++i)
#pragma unroll
                for (int j = 0; j < 4; ++j)
                    acc[i][j] += a[i] * b[j];
        }
    }

#pragma unroll
    for (int i = 0; i < 4; ++i) {
        const int m = m0 + ty * 4 + i;
        float4 v;
        v.x = acc[i][0] + bs[0];
        v.y = acc[i][1] + bs[1];
        v.z = acc[i][2] + bs[2];
        v.w = acc[i][3] + bs[3];
        *(float4*)(C + (size_t)m * N + n0 + tx * 4) = v;
    }
}

// ---------------------------------------------------------------------------
// Pack W_hh [1024][1024] into per-slice, LDS-ready layout:
//   Wpk[s][ ((c*4+i)*8+jg)*32+kg ] (float4) = W[s*32+jg*4+i][4*(c*32+kg)..+3]
// so the scan's per-(c,i) wave read is 64 consecutive float4s (conflict-free).
// ---------------------------------------------------------------------------
__global__ __launch_bounds__(256) void pack_whh(
    const float* __restrict__ W, float4* __restrict__ Wpk)
{
    const int fid = blockIdx.x * 256 + threadIdx.x;   // 0..262143
    const int s   = fid >> 13;
    const int idx = fid & 8191;
    const int kg  = idx & 31;
    const int r   = idx >> 5;
    const int jg  = r & 7;
    const int q   = r >> 3;
    const int i   = q & 3;
    const int c   = q >> 2;
    const int j   = s * 32 + jg * 4 + i;
    const int kf  = c * 32 + kg;
    Wpk[fid] = *(const float4*)(W + (size_t)j * HID_ + 4 * kf);
}

// ---------------------------------------------------------------------------
// Weight-stationary persistent scan. 256 WGs x 256 threads, 1 WG/CU (146 KB
// LDS). WG = (slice s = blockIdx>>3: 32 neurons) x (batch-group bg =
// blockIdx&7: 4 batches). W slice lives in LDS for the whole kernel; h is
// exchanged through x (in place: xp in, h out) with a per-group barrier.
// Thread (jg=tid>>5, kg=tid&31) owns 4 neurons x 4 batches over a 32-wide
// k-chunk; split-k partials reduced through LDS.
// ---------------------------------------------------------------------------
__global__ __launch_bounds__(256, 1) void rnn_scan_ws(
    const float4* __restrict__ Wpk,   // [32][8192] float4
    float* __restrict__ x)            // [B,S,H]
{
    extern __shared__ char smem[];
    float4* Wl  = (float4*)smem;                  // 131072 B
    float*  hl  = (float*)(smem + 131072);        // stage 16384 B / red 18432 B (aliased)
    float4* hl4 = (float4*)hl;
    float*  red = hl;

    const int wg  = blockIdx.x;
    const int bg  = wg & 7;
    const int s   = wg >> 3;
    const int tid = threadIdx.x;
    const int jg  = tid >> 5;
    const int kg  = tid & 31;
    const int b0  = bg * 4;
    const int sb  = tid >> 6;      // staging batch 0..3
    const int sk  = tid & 63;      // staging kf base

    unsigned* cntp = &g_cnt[bg].v;
    unsigned* ackp = &g_ack[bg].v;

    // load weight slice into LDS (coalesced, once)
    const float4* wsrc = Wpk + (size_t)s * 8192;
#pragma unroll
    for (int it = 0; it < 32; ++it)
        Wl[it * 256 + tid] = wsrc[it * 256 + tid];
    __syncthreads();

    for (int t = 0; t < S_; ++t) {
        if (t > 0) {
            if (tid == 0) {
                while (__hip_atomic_load(cntp, __ATOMIC_ACQUIRE,
                                         __HIP_MEMORY_SCOPE_AGENT) < (unsigned)(32 * t))
                    __builtin_amdgcn_s_sleep(1);
            }
            __syncthreads();   // also protects red (prev step) before staging
            const float* hsrc = x + ((size_t)(b0 + sb) * S_ + (t - 1)) * HID_;
#pragma unroll
            for (int q = 0; q < 4; ++q) {
                const int kf = sk + q * 64;
                float4 v;
                v.x = aload(hsrc + 4 * kf + 0);
                v.y = aload(hsrc + 4 * kf + 1);
                v.z = aload(hsrc + 4 * kf + 2);
                v.w = aload(hsrc + 4 * kf + 3);
                hl4[sb * 256 + kf] = v;
            }
        } else {
#pragma unroll
            for (int q = 0; q < 4; ++q)
                hl4[sb * 256 + sk + q * 64] = make_float4(0.f, 0.f, 0.f, 0.f);
        }
        __syncthreads();

        float acc[4][4];
#pragma unroll
        for (int i = 0; i < 4; ++i)
#pragma unroll
            for (int b = 0; b < 4; ++b) acc[i][b] = 0.f;

#pragma unroll
        for (int c = 0; c < 8; ++c) {
            float4 wv[4], hv[4];
#pragma unroll
            for (int i = 0; i < 4; ++i)
                wv[i] = Wl[((c * 4 + i) * 8 + jg) * 32 + kg];
#pragma unroll
            for (int b = 0; b < 4; ++b)
                hv[b] = hl4[b * 256 + c * 32 + kg];
#pragma unroll
            for (int i = 0; i < 4; ++i)
#pragma unroll
                for (int b = 0; b < 4; ++b)
                    acc[i][b] += wv[i].x * hv[b].x + wv[i].y * hv[b].y
                               + wv[i].z * hv[b].z + wv[i].w * hv[b].w;
        }
        __syncthreads();   // h reads done before red overwrite

#pragma unroll
        for (int i = 0; i < 4; ++i)
#pragma unroll
            for (int b = 0; b < 4; ++b)
                red[((jg * 4 + i) * 4 + b) * 36 + kg] = acc[i][b];
        __syncthreads();

        if (tid < 128) {
            const int o = tid;
            const float4* rp = (const float4*)(red + o * 36);  // 144B rows: 16B aligned
            float4 r0 = rp[0], r1 = rp[1], r2 = rp[2], r3 = rp[3];
            float4 r4 = rp[4], r5 = rp[5], r6 = rp[6], r7 = rp[7];
            float sum = ((r0.x + r0.y + r0.z + r0.w) + (r1.x + r1.y + r1.z + r1.w))
                      + ((r2.x + r2.y + r2.z + r2.w) + (r3.x + r3.y + r3.z + r3.w))
                      + ((r4.x + r4.y + r4.z + r4.w) + (r5.x + r5.y + r5.z + r5.w))
                      + ((r6.x + r6.y + r6.z + r6.w) + (r7.x + r7.y + r7.z + r7.w));
            const int jl = o >> 2, b = o & 3;
            float* px = x + ((size_t)(b0 + b) * S_ + t) * HID_ + s * 32 + jl;
            const float xp = *px;           // xp written by prior GEMM (plain ok)
            astore(px, tanhf(xp + sum));    // agent store: coherent for the group
        }
        __syncthreads();   // drains stores (vmcnt) + red reads done
        if (tid == 0 && t < S_ - 1) atomicAdd(cntp, 1u);
    }

    // epilogue: reset barrier state so the next launch starts at 0
    __syncthreads();
    if (tid == 0) {
        atomicAdd(ackp, 1u);
        if (s == 0) {
            while (__hip_atomic_load(ackp, __ATOMIC_ACQUIRE,
                                     __HIP_MEMORY_SCOPE_AGENT) < 32u)
                __builtin_amdgcn_s_sleep(1);
            __hip_atomic_store(cntp, 0u, __ATOMIC_RELAXED, __HIP_MEMORY_SCOPE_AGENT);
            __hip_atomic_store(ackp, 0u, __ATOMIC_RELEASE, __HIP_MEMORY_SCOPE_AGENT);
        }
    }
}

__global__ __launch_bounds__(256) void copy4(
    const float4* __restrict__ src, float4* __restrict__ dst, int n4)
{
    const int i = blockIdx.x * 256 + threadIdx.x;
    if (i < n4) dst[i] = src[i];
}

extern "C" void kernel_launch(void* const* d_in, const int* in_sizes, int n_in,
                              void* d_out, int out_size, void* d_ws, size_t ws_size,
                              hipStream_t stream)
{
    const int*   tokens = (const int*)  d_in[0];
    const float* emb    = (const float*)d_in[1];
    const float* W_ih0  = (const float*)d_in[2];
    const float* W_hh0  = (const float*)d_in[3];
    const float* b_ih0  = (const float*)d_in[4];
    const float* b_hh0  = (const float*)d_in[5];
    const float* W_ih1  = (const float*)d_in[6];
    const float* W_hh1  = (const float*)d_in[7];
    const float* b_ih1  = (const float*)d_in[8];
    const float* b_hh1  = (const float*)d_in[9];
    const float* W_out  = (const float*)d_in[10];
    const float* b_out  = (const float*)d_in[11];
    float* out = (float*)d_out;

    float* buf = (float*)d_ws;            // ONE [B,S,H] fp32 buffer (64 MiB)
    float4* Wpk = (float4*)d_out;         // 4 MiB: packed W_hh (per phase)
    float*  tmp = (float*)d_out;          // xp1 chunk bounce

    const size_t scan_lds = 131072 + 18432;   // 146 KB < 160 KB, 1 WG/CU
    hipFuncSetAttribute((const void*)rnn_scan_ws,
                        hipFuncAttributeMaxDynamicSharedMemorySize, (int)scan_lds);

    // 1) xp0 = gather(emb,tokens) @ W_ih0^T + b_ih0 + b_hh0  -> buf
    gemm_bias<<<dim3(HID_ / 64, M_ / 64), 256, 0, stream>>>(
        emb, tokens, W_ih0, b_ih0, b_hh0, buf, M_, EMB_, HID_);

    // 2) layer-0 scan (weight-stationary, in place on buf)
    pack_whh<<<1024, 256, 0, stream>>>(W_hh0, Wpk);
    rnn_scan_ws<<<256, 256, scan_lds, stream>>>(Wpk, buf);

    // 3) xp1 = h0 @ W_ih1^T + b_ih1 + b_hh1, chunked through d_out
    for (int c = 0; c < 16; ++c) {
        const float* Ac = buf + (size_t)c * 1024 * HID_;
        gemm_bias<<<dim3(HID_ / 64, 1024 / 64), 256, 0, stream>>>(
            Ac, nullptr, W_ih1, b_ih1, b_hh1, tmp, 1024, HID_, HID_);
        copy4<<<1024, 256, 0, stream>>>(
            (const float4*)tmp, (float4*)(buf + (size_t)c * 1024 * HID_),
            1024 * HID_ / 4);
    }

    // 4) layer-1 scan
    pack_whh<<<1024, 256, 0, stream>>>(W_hh1, Wpk);
    rnn_scan_ws<<<256, 256, scan_lds, stream>>>(Wpk, buf);

    // 5) out = h1 @ W_out^T + b_out (fully rewrites d_out)
    gemm_bias<<<dim3(LAB_ / 64, M_ / 64), 256, 0, stream>>>(
        buf, nullptr, W_out, b_out, nullptr, out, M_, HID_, LAB_);
}